// Round 4
// baseline (146.738 us; speedup 1.0000x reference)
//
#include <hip/hip_runtime.h>

#define NPG 32

typedef _Float16 half8 __attribute__((ext_vector_type(8)));
typedef _Float16 half4v __attribute__((ext_vector_type(4)));
typedef float f32x4 __attribute__((ext_vector_type(4)));

#define MFMA16(a, b, c) __builtin_amdgcn_mfma_f32_16x16x32_f16(a, b, c, 0, 0, 0)

// ---------------------------------------------------------------------------
// Nibble-packed neighbor counts, one array copy per XCD so the atomic RMWs
// stay in the local (non-coherent) L2 instead of write-through to fabric.
// cnt[copy][node_d][4 u32]; s in 0..31 -> word s>>3, nibble s&7.
// ---------------------------------------------------------------------------
template <bool MULTI>
__global__ void build_cnt(const int4* __restrict__ src4,
                          const int4* __restrict__ dst4,
                          unsigned* __restrict__ cnt, int E4,
                          size_t copyStride) {
    int e = blockIdx.x * blockDim.x + threadIdx.x;
    if (e >= E4) return;
    unsigned* base = cnt;
    if (MULTI) {
        unsigned xcc;
        asm volatile("s_getreg_b32 %0, hwreg(HW_REG_XCC_ID)" : "=s"(xcc));
        base = cnt + (size_t)xcc * copyStride;
    }
    int4 s4 = src4[e];
    int4 d4 = dst4[e];
#pragma unroll
    for (int j = 0; j < 4; ++j) {
        int s = ((const int*)&s4)[j] & 31;
        int d = ((const int*)&d4)[j];
        unsigned inc = 1u << (4 * (s & 7));
        if (MULTI)
            __hip_atomic_fetch_add(&base[d * 4 + (s >> 3)], inc,
                                   __ATOMIC_RELAXED,
                                   __HIP_MEMORY_SCOPE_WORKGROUP);
        else
            atomicAdd(&base[d * 4 + (s >> 3)], inc);
    }
}

// ---------------------------------------------------------------------------
// Weight prep: per 16x16x32 B-tile (kt,ct), lane l holds W[kt*32+(l>>4)*8+j]
// [ct*16+(l&15)], j=0..7, as f16 hi plane + f16 lo plane (residual).
// [w0a:0..3][w0b:4..11][w1a:12..19][w1b:20..27]
// ---------------------------------------------------------------------------
__global__ __launch_bounds__(64) void prep_w(const float* __restrict__ w0a,
                                             const float* __restrict__ w0b,
                                             const float* __restrict__ w1a,
                                             const float* __restrict__ w1b,
                                             _Float16* __restrict__ wf) {
    int b = blockIdx.x;  // 0..27
    int l = threadIdx.x;
    const float* W;
    int fi;
    if (b < 4) {
        W = w0a; fi = b;
    } else if (b < 12) {
        W = w0b; fi = b - 4;
    } else if (b < 20) {
        W = w1a; fi = b - 12;
    } else {
        W = w1b; fi = b - 20;
    }
    int kt = fi >> 2, ct = fi & 3;
    int q = l >> 4, r = l & 15;
    half8 hi, lo;
#pragma unroll
    for (int j = 0; j < 8; ++j) {
        float w = W[(kt * 32 + q * 8 + j) * 64 + ct * 16 + r];
        _Float16 h = (_Float16)w;
        hi[j] = h;
        lo[j] = (_Float16)(w - (float)h);
    }
    *(half8*)(wf + b * 1024 + l * 8) = hi;
    *(half8*)(wf + b * 1024 + 512 + l * 8) = lo;
}

// ---------------------------------------------------------------------------
// MLP core: acc[mt][ct] = bias + H[32xK] @ (Whi + Wlo)[Kx64]
// ---------------------------------------------------------------------------
template <int KT>
__device__ __forceinline__ void mlp_core(const _Float16* Ha,
                                         const _Float16* __restrict__ wf,
                                         int fragBase,
                                         const float* __restrict__ bias, int q,
                                         int r, int l, f32x4 acc[2][4]) {
    half8 A[2][KT];
#pragma unroll
    for (int mt = 0; mt < 2; ++mt)
#pragma unroll
        for (int kt = 0; kt < KT; ++kt)
            A[mt][kt] =
                *(const half8*)&Ha[(mt * 16 + r) * 72 + kt * 32 + q * 8];
#pragma unroll
    for (int ct = 0; ct < 4; ++ct) {
        float b = bias[ct * 16 + r];
        f32x4 a0 = {b, b, b, b}, a1 = {b, b, b, b};
#pragma unroll
        for (int kt = 0; kt < KT; ++kt) {
            const _Float16* base = wf + (fragBase + kt * 4 + ct) * 1024;
            half8 whi = *(const half8*)(base + l * 8);
            half8 wlo = *(const half8*)(base + 512 + l * 8);
            a0 = MFMA16(A[0][kt], whi, a0);
            a0 = MFMA16(A[0][kt], wlo, a0);
            a1 = MFMA16(A[1][kt], whi, a1);
            a1 = MFMA16(A[1][kt], wlo, a1);
        }
        acc[0][ct] = a0;
        acc[1][ct] = a1;
    }
}

// ---------------------------------------------------------------------------
// Fused per-subgraph kernel: one wave per subgraph, all matmuls on MFMA.
// LDS: Ha[32][72] + HT[64][40] + Cn[32][40] f16 = 12288 B.
// ---------------------------------------------------------------------------
__global__ __launch_bounds__(64, 4) void seal_fused(
    const int* __restrict__ labels, const float* __restrict__ emb,
    const float* __restrict__ b0a, const float* __restrict__ b0b,
    const float* __restrict__ b1a, const float* __restrict__ b1b,
    const float* __restrict__ ws1, const float* __restrict__ bs1,
    const float* __restrict__ ws2, const float* __restrict__ bs2,
    const unsigned* __restrict__ cnt, int ncopy, size_t copyStride,
    const _Float16* __restrict__ wf, float* __restrict__ out) {
    const int g = blockIdx.x;
    const int l = threadIdx.x;
    const int q = l >> 4, r = l & 15;

    __shared__ __align__(16) _Float16 Ha[32 * 72];
    __shared__ __align__(16) _Float16 HT[64 * 40];
    __shared__ __align__(16) _Float16 Cn[32 * 40];

    // ---- Cnt tile: sum per-XCD copies, unpack nibbles, add I ----
    {
        int d = l & 31, part = l >> 5;
        const unsigned* cg = cnt + ((size_t)g * 32 + d) * 4 + part * 2;
        unsigned c0 = 0, c1 = 0;
        for (int c = 0; c < ncopy; ++c) {
            c0 += cg[c * copyStride];
            c1 += cg[c * copyStride + 1];
        }
#pragma unroll
        for (int i = 0; i < 8; ++i) {
            int s0 = part * 16 + i;
            int s1 = part * 16 + 8 + i;
            float v0 = (float)((c0 >> (4 * i)) & 15u) + (s0 == d ? 1.f : 0.f);
            float v1 = (float)((c1 >> (4 * i)) & 15u) + (s1 == d ? 1.f : 0.f);
            Cn[d * 40 + s0] = (_Float16)v0;
            Cn[d * 40 + s1] = (_Float16)v1;
        }
    }

    // ---- embedding -> HT[f][n], f in 0..31 (B-operand layout for agg0) ----
    {
        int n = l & 31, hf = l >> 5;
        int lab = labels[g * NPG + n];
        lab = min(max(lab, 0), 50);
        const float* er = emb + lab * 32 + hf * 16;
#pragma unroll
        for (int j = 0; j < 16; ++j) {
            float v = (lab != 0) ? er[j] : 0.f;
            HT[(hf * 16 + j) * 40 + n] = (_Float16)v;
        }
    }
    __syncthreads();

    // Cnt A-frags, held in regs for both aggs
    half8 cA0 = *(const half8*)&Cn[(0 * 16 + r) * 40 + q * 8];
    half8 cA1 = *(const half8*)&Cn[(1 * 16 + r) * 40 + q * 8];

    // ---- agg0: Ha[32 nodes][32 f] = (I+C) @ H0 ----
    {
        half8 b0 = *(const half8*)&HT[(0 * 16 + r) * 40 + q * 8];
        half8 b1 = *(const half8*)&HT[(1 * 16 + r) * 40 + q * 8];
        f32x4 z = {0.f, 0.f, 0.f, 0.f};
        f32x4 a00 = MFMA16(cA0, b0, z), a01 = MFMA16(cA0, b1, z);
        f32x4 a10 = MFMA16(cA1, b0, z), a11 = MFMA16(cA1, b1, z);
        __syncthreads();
#pragma unroll
        for (int i = 0; i < 4; ++i) {
            Ha[(q * 4 + i) * 72 + r] = (_Float16)a00[i];
            Ha[(q * 4 + i) * 72 + 16 + r] = (_Float16)a01[i];
            Ha[(16 + q * 4 + i) * 72 + r] = (_Float16)a10[i];
            Ha[(16 + q * 4 + i) * 72 + 16 + r] = (_Float16)a11[i];
        }
    }
    __syncthreads();

    f32x4 acc[2][4];

    // ---- MLP0a: relu(Ha[32x32] @ w0a + b0a) -> Ha (in-place, reg-staged) ----
    mlp_core<1>(Ha, wf, 0, b0a, q, r, l, acc);
    __syncthreads();
#pragma unroll
    for (int mt = 0; mt < 2; ++mt)
#pragma unroll
        for (int ct = 0; ct < 4; ++ct)
#pragma unroll
            for (int i = 0; i < 4; ++i)
                Ha[(mt * 16 + q * 4 + i) * 72 + ct * 16 + r] =
                    (_Float16)fmaxf(acc[mt][ct][i], 0.f);
    __syncthreads();

    // ---- MLP0b: relu(Ha @ w0b + b0b) -> HT[feat][node] (B-layout) ----
    mlp_core<2>(Ha, wf, 4, b0b, q, r, l, acc);
    __syncthreads();
#pragma unroll
    for (int mt = 0; mt < 2; ++mt)
#pragma unroll
        for (int ct = 0; ct < 4; ++ct) {
            half4v p;
#pragma unroll
            for (int i = 0; i < 4; ++i)
                p[i] = (_Float16)fmaxf(acc[mt][ct][i], 0.f);
            *(half4v*)&HT[(ct * 16 + r) * 40 + mt * 16 + q * 4] = p;
        }
    __syncthreads();

    // ---- agg1: Ha[32][64] = (I+C) @ H1  (B from HT) ----
    {
        f32x4 z = {0.f, 0.f, 0.f, 0.f};
#pragma unroll
        for (int ct = 0; ct < 4; ++ct) {
            half8 bf = *(const half8*)&HT[(ct * 16 + r) * 40 + q * 8];
            acc[0][ct] = MFMA16(cA0, bf, z);
            acc[1][ct] = MFMA16(cA1, bf, z);
        }
        __syncthreads();
#pragma unroll
        for (int mt = 0; mt < 2; ++mt)
#pragma unroll
            for (int ct = 0; ct < 4; ++ct)
#pragma unroll
                for (int i = 0; i < 4; ++i)
                    Ha[(mt * 16 + q * 4 + i) * 72 + ct * 16 + r] =
                        (_Float16)acc[mt][ct][i];
    }
    __syncthreads();

    // ---- MLP1a: relu(Ha @ w1a + b1a) -> Ha (in-place) ----
    mlp_core<2>(Ha, wf, 12, b1a, q, r, l, acc);
    __syncthreads();
#pragma unroll
    for (int mt = 0; mt < 2; ++mt)
#pragma unroll
        for (int ct = 0; ct < 4; ++ct)
#pragma unroll
            for (int i = 0; i < 4; ++i)
                Ha[(mt * 16 + q * 4 + i) * 72 + ct * 16 + r] =
                    (_Float16)fmaxf(acc[mt][ct][i], 0.f);
    __syncthreads();

    // ---- MLP1b + relu + mean pool ----
    mlp_core<2>(Ha, wf, 20, b1b, q, r, l, acc);
    float ps[4];
#pragma unroll
    for (int ct = 0; ct < 4; ++ct) {
        ps[ct] = 0.f;
#pragma unroll
        for (int mt = 0; mt < 2; ++mt)
#pragma unroll
            for (int i = 0; i < 4; ++i) ps[ct] += fmaxf(acc[mt][ct][i], 0.f);
        ps[ct] += __shfl_xor(ps[ct], 16, 64);
        ps[ct] += __shfl_xor(ps[ct], 32, 64);
    }
    __syncthreads();
    float* hg = (float*)Ha;
    if (l < 16) {
#pragma unroll
        for (int ct = 0; ct < 4; ++ct) hg[ct * 16 + l] = ps[ct] * (1.f / 32.f);
    }
    __syncthreads();

    // ---- scorer: relu(hg @ ws1 + bs1) @ ws2 + bs2 ----
    float acc0 = bs1[l];
#pragma unroll
    for (int kq = 0; kq < 16; ++kq) {
        const float4 h4 = *reinterpret_cast<const float4*>(&hg[kq * 4]);
        acc0 = fmaf(h4.x, ws1[(kq * 4 + 0) * 64 + l], acc0);
        acc0 = fmaf(h4.y, ws1[(kq * 4 + 1) * 64 + l], acc0);
        acc0 = fmaf(h4.z, ws1[(kq * 4 + 2) * 64 + l], acc0);
        acc0 = fmaf(h4.w, ws1[(kq * 4 + 3) * 64 + l], acc0);
    }
    float p = fmaxf(acc0, 0.f) * ws2[l];
#pragma unroll
    for (int off = 32; off > 0; off >>= 1) p += __shfl_xor(p, off, 64);
    if (l == 0) out[g] = p + bs2[0];
}

// ---------------------------------------------------------------------------
extern "C" void kernel_launch(void* const* d_in, const int* in_sizes, int n_in,
                              void* d_out, int out_size, void* d_ws,
                              size_t ws_size, hipStream_t stream) {
    const int* labels = (const int*)d_in[0];
    const int* src = (const int*)d_in[1];
    const int* dst = (const int*)d_in[2];
    const float* emb = (const float*)d_in[4];
    const float* w0a = (const float*)d_in[5];
    const float* b0a = (const float*)d_in[6];
    const float* w0b = (const float*)d_in[7];
    const float* b0b = (const float*)d_in[8];
    const float* w1a = (const float*)d_in[9];
    const float* b1a = (const float*)d_in[10];
    const float* w1b = (const float*)d_in[11];
    const float* b1b = (const float*)d_in[12];
    const float* ws1 = (const float*)d_in[13];
    const float* bs1 = (const float*)d_in[14];
    const float* ws2 = (const float*)d_in[15];
    const float* bs2 = (const float*)d_in[16];
    float* out = (float*)d_out;

    const int N = in_sizes[0];  // 262144 nodes
    const int E = in_sizes[1];  // 2097152 edges
    const int Gn = out_size;    // 8192 subgraphs

    const size_t copyBytes = (size_t)N * 16;        // 4 MB per copy
    const size_t copyStride = (size_t)N * 4;        // in u32 elements
    int ncopy = (ws_size >= copyBytes * 8 + 65536) ? 8 : 1;

    unsigned* cnt = (unsigned*)d_ws;
    _Float16* wf = (_Float16*)((char*)d_ws + copyBytes * ncopy);

    hipMemsetAsync(cnt, 0, copyBytes * ncopy, stream);
    const int E4 = E / 4;
    if (ncopy == 8)
        build_cnt<true><<<(E4 + 255) / 256, 256, 0, stream>>>(
            (const int4*)src, (const int4*)dst, cnt, E4, copyStride);
    else
        build_cnt<false><<<(E4 + 255) / 256, 256, 0, stream>>>(
            (const int4*)src, (const int4*)dst, cnt, E4, copyStride);
    prep_w<<<28, 64, 0, stream>>>(w0a, w0b, w1a, w1b, wf);
    seal_fused<<<Gn, 64, 0, stream>>>(labels, emb, b0a, b0b, b1a, b1b, ws1,
                                      bs1, ws2, bs2, cnt, ncopy, copyStride,
                                      wf, out);
}

// Round 5
// 77.875 us; speedup vs baseline: 1.8843x; 1.8843x over previous
//
#include <hip/hip_runtime.h>

#define NPG 32
#define BUCKETS 256
#define BCAP 10240  // per-bucket capacity: mean 8192, sigma ~88 -> +23 sigma

typedef _Float16 half8 __attribute__((ext_vector_type(8)));
typedef _Float16 half4v __attribute__((ext_vector_type(4)));
typedef float f32x4 __attribute__((ext_vector_type(4)));

#define MFMA16(a, b, c) __builtin_amdgcn_mfma_f32_16x16x32_f16(a, b, c, 0, 0, 0)

// ---------------------------------------------------------------------------
// K1: partition edges into 256 buckets (32 graphs each). Per block: LDS
// histogram, ONE global atomic per bucket (65K total vs 2M), LDS-cursor
// scatter of packed (d<<5)|s words into per-bucket regions.
// ---------------------------------------------------------------------------
__global__ __launch_bounds__(256) void part_edges(
    const int4* __restrict__ src4, const int4* __restrict__ dst4, int E4,
    unsigned* __restrict__ gFill, unsigned* __restrict__ packed) {
    __shared__ unsigned hist[BUCKETS];
    __shared__ unsigned cursor[BUCKETS];
    const int t = threadIdx.x;
    const int b4 = blockIdx.x * 2048;
    unsigned pk[32];
#pragma unroll
    for (int k = 0; k < 8; ++k) {
        int i4 = b4 + k * 256 + t;
        if (i4 < E4) {
            int4 s4 = src4[i4];
            int4 d4 = dst4[i4];
#pragma unroll
            for (int j = 0; j < 4; ++j) {
                unsigned d = (unsigned)((const int*)&d4)[j];
                unsigned s = (unsigned)((const int*)&s4)[j] & 31u;
                pk[k * 4 + j] = (d << 5) | s;  // bucket=pk>>15, gL=(pk>>10)&31
            }
        } else {
#pragma unroll
            for (int j = 0; j < 4; ++j) pk[k * 4 + j] = 0xFFFFFFFFu;
        }
    }
    hist[t] = 0;
    __syncthreads();
#pragma unroll
    for (int k = 0; k < 32; ++k)
        if (pk[k] != 0xFFFFFFFFu) atomicAdd(&hist[pk[k] >> 15], 1u);
    __syncthreads();
    cursor[t] = atomicAdd(&gFill[t], hist[t]);  // reserve block's range
    __syncthreads();
#pragma unroll
    for (int k = 0; k < 32; ++k) {
        if (pk[k] == 0xFFFFFFFFu) continue;
        unsigned b = pk[k] >> 15;
        unsigned slot = atomicAdd(&cursor[b], 1u);
        if (slot < BCAP) packed[b * BCAP + slot] = pk[k];
    }
}

// ---------------------------------------------------------------------------
// K2: per bucket, accumulate nibble-packed counts for its 32 graphs in LDS,
// then write the 16KB block out linearly (fully overwrites cnt -> no memset).
// cnt[node*4+w], node=(b*32+gl)*32+d  ==  b*4096 + gl*128 + d*4 + w (linear).
// ---------------------------------------------------------------------------
__global__ __launch_bounds__(256) void count_edges(
    const unsigned* __restrict__ gFill, const unsigned* __restrict__ packed,
    unsigned* __restrict__ cnt) {
    __shared__ unsigned C[32 * 128];  // 16 KB
    const int b = blockIdx.x, t = threadIdx.x;
#pragma unroll
    for (int i = 0; i < 16; ++i) C[i * 256 + t] = 0;
    __syncthreads();
    unsigned n = gFill[b];
    if (n > BCAP) n = BCAP;
    const unsigned* pb = packed + (size_t)b * BCAP;
    for (unsigned i = t; i < n; i += 256) {
        unsigned pk = pb[i];
        unsigned gl = (pk >> 10) & 31u, d = (pk >> 5) & 31u, s = pk & 31u;
        atomicAdd(&C[gl * 128 + d * 4 + (s >> 3)], 1u << (4 * (s & 7)));
    }
    __syncthreads();
    unsigned* cg = cnt + (size_t)b * 4096;
#pragma unroll
    for (int i = 0; i < 16; ++i) cg[i * 256 + t] = C[i * 256 + t];
}

// ---------------------------------------------------------------------------
// Weight prep: per 16x16x32 B-tile (kt,ct), lane l holds W[kt*32+(l>>4)*8+j]
// [ct*16+(l&15)], j=0..7, as f16 hi plane + f16 lo plane (residual).
// [w0a:0..3][w0b:4..11][w1a:12..19][w1b:20..27]
// ---------------------------------------------------------------------------
__global__ __launch_bounds__(64) void prep_w(const float* __restrict__ w0a,
                                             const float* __restrict__ w0b,
                                             const float* __restrict__ w1a,
                                             const float* __restrict__ w1b,
                                             _Float16* __restrict__ wf) {
    int b = blockIdx.x;  // 0..27
    int l = threadIdx.x;
    const float* W;
    int fi;
    if (b < 4) {
        W = w0a; fi = b;
    } else if (b < 12) {
        W = w0b; fi = b - 4;
    } else if (b < 20) {
        W = w1a; fi = b - 12;
    } else {
        W = w1b; fi = b - 20;
    }
    int kt = fi >> 2, ct = fi & 3;
    int q = l >> 4, r = l & 15;
    half8 hi, lo;
#pragma unroll
    for (int j = 0; j < 8; ++j) {
        float w = W[(kt * 32 + q * 8 + j) * 64 + ct * 16 + r];
        _Float16 h = (_Float16)w;
        hi[j] = h;
        lo[j] = (_Float16)(w - (float)h);
    }
    *(half8*)(wf + b * 1024 + l * 8) = hi;
    *(half8*)(wf + b * 1024 + 512 + l * 8) = lo;
}

// ---------------------------------------------------------------------------
// MLP core: acc[mt][ct] = bias + H[32xK] @ (Whi + Wlo)[Kx64]
// ---------------------------------------------------------------------------
template <int KT>
__device__ __forceinline__ void mlp_core(const _Float16* Ha,
                                         const _Float16* __restrict__ wf,
                                         int fragBase,
                                         const float* __restrict__ bias, int q,
                                         int r, int l, f32x4 acc[2][4]) {
    half8 A[2][KT];
#pragma unroll
    for (int mt = 0; mt < 2; ++mt)
#pragma unroll
        for (int kt = 0; kt < KT; ++kt)
            A[mt][kt] =
                *(const half8*)&Ha[(mt * 16 + r) * 72 + kt * 32 + q * 8];
#pragma unroll
    for (int ct = 0; ct < 4; ++ct) {
        float b = bias[ct * 16 + r];
        f32x4 a0 = {b, b, b, b}, a1 = {b, b, b, b};
#pragma unroll
        for (int kt = 0; kt < KT; ++kt) {
            const _Float16* base = wf + (fragBase + kt * 4 + ct) * 1024;
            half8 whi = *(const half8*)(base + l * 8);
            half8 wlo = *(const half8*)(base + 512 + l * 8);
            a0 = MFMA16(A[0][kt], whi, a0);
            a0 = MFMA16(A[0][kt], wlo, a0);
            a1 = MFMA16(A[1][kt], whi, a1);
            a1 = MFMA16(A[1][kt], wlo, a1);
        }
        acc[0][ct] = a0;
        acc[1][ct] = a1;
    }
}

// ---------------------------------------------------------------------------
// Fused per-subgraph kernel: one wave per subgraph, all matmuls on MFMA.
// LDS: Ha[32][72] + HT[64][40] + Cn[32][40] f16 = 12288 B.
// ---------------------------------------------------------------------------
__global__ __launch_bounds__(64, 4) void seal_fused(
    const int* __restrict__ labels, const float* __restrict__ emb,
    const float* __restrict__ b0a, const float* __restrict__ b0b,
    const float* __restrict__ b1a, const float* __restrict__ b1b,
    const float* __restrict__ ws1, const float* __restrict__ bs1,
    const float* __restrict__ ws2, const float* __restrict__ bs2,
    const unsigned* __restrict__ cnt, const _Float16* __restrict__ wf,
    float* __restrict__ out) {
    const int g = blockIdx.x;
    const int l = threadIdx.x;
    const int q = l >> 4, r = l & 15;

    __shared__ __align__(16) _Float16 Ha[32 * 72];
    __shared__ __align__(16) _Float16 HT[64 * 40];
    __shared__ __align__(16) _Float16 Cn[32 * 40];

    // ---- Cnt tile: unpack nibbles, add I (GIN eps=0 self term) ----
    {
        int d = l & 31, part = l >> 5;
        const unsigned* cg = cnt + ((size_t)g * 32 + d) * 4 + part * 2;
        unsigned c0 = cg[0], c1 = cg[1];
#pragma unroll
        for (int i = 0; i < 8; ++i) {
            int s0 = part * 16 + i;
            int s1 = part * 16 + 8 + i;
            float v0 = (float)((c0 >> (4 * i)) & 15u) + (s0 == d ? 1.f : 0.f);
            float v1 = (float)((c1 >> (4 * i)) & 15u) + (s1 == d ? 1.f : 0.f);
            Cn[d * 40 + s0] = (_Float16)v0;
            Cn[d * 40 + s1] = (_Float16)v1;
        }
    }

    // ---- embedding -> HT[f][n], f in 0..31 (B-operand layout for agg0) ----
    {
        int n = l & 31, hf = l >> 5;
        int lab = labels[g * NPG + n];
        lab = min(max(lab, 0), 50);
        const float* er = emb + lab * 32 + hf * 16;
#pragma unroll
        for (int j = 0; j < 16; ++j) {
            float v = (lab != 0) ? er[j] : 0.f;
            HT[(hf * 16 + j) * 40 + n] = (_Float16)v;
        }
    }
    __syncthreads();

    // Cnt A-frags, held in regs for both aggs
    half8 cA0 = *(const half8*)&Cn[(0 * 16 + r) * 40 + q * 8];
    half8 cA1 = *(const half8*)&Cn[(1 * 16 + r) * 40 + q * 8];

    // ---- agg0: Ha[32 nodes][32 f] = (I+C) @ H0 ----
    {
        half8 b0 = *(const half8*)&HT[(0 * 16 + r) * 40 + q * 8];
        half8 b1 = *(const half8*)&HT[(1 * 16 + r) * 40 + q * 8];
        f32x4 z = {0.f, 0.f, 0.f, 0.f};
        f32x4 a00 = MFMA16(cA0, b0, z), a01 = MFMA16(cA0, b1, z);
        f32x4 a10 = MFMA16(cA1, b0, z), a11 = MFMA16(cA1, b1, z);
        __syncthreads();
#pragma unroll
        for (int i = 0; i < 4; ++i) {
            Ha[(q * 4 + i) * 72 + r] = (_Float16)a00[i];
            Ha[(q * 4 + i) * 72 + 16 + r] = (_Float16)a01[i];
            Ha[(16 + q * 4 + i) * 72 + r] = (_Float16)a10[i];
            Ha[(16 + q * 4 + i) * 72 + 16 + r] = (_Float16)a11[i];
        }
    }
    __syncthreads();

    f32x4 acc[2][4];

    // ---- MLP0a: relu(Ha[32x32] @ w0a + b0a) -> Ha (in-place, reg-staged) ----
    mlp_core<1>(Ha, wf, 0, b0a, q, r, l, acc);
    __syncthreads();
#pragma unroll
    for (int mt = 0; mt < 2; ++mt)
#pragma unroll
        for (int ct = 0; ct < 4; ++ct)
#pragma unroll
            for (int i = 0; i < 4; ++i)
                Ha[(mt * 16 + q * 4 + i) * 72 + ct * 16 + r] =
                    (_Float16)fmaxf(acc[mt][ct][i], 0.f);
    __syncthreads();

    // ---- MLP0b: relu(Ha @ w0b + b0b) -> HT[feat][node] (B-layout) ----
    mlp_core<2>(Ha, wf, 4, b0b, q, r, l, acc);
    __syncthreads();
#pragma unroll
    for (int mt = 0; mt < 2; ++mt)
#pragma unroll
        for (int ct = 0; ct < 4; ++ct) {
            half4v p;
#pragma unroll
            for (int i = 0; i < 4; ++i)
                p[i] = (_Float16)fmaxf(acc[mt][ct][i], 0.f);
            *(half4v*)&HT[(ct * 16 + r) * 40 + mt * 16 + q * 4] = p;
        }
    __syncthreads();

    // ---- agg1: Ha[32][64] = (I+C) @ H1  (B from HT) ----
    {
        f32x4 z = {0.f, 0.f, 0.f, 0.f};
#pragma unroll
        for (int ct = 0; ct < 4; ++ct) {
            half8 bf = *(const half8*)&HT[(ct * 16 + r) * 40 + q * 8];
            acc[0][ct] = MFMA16(cA0, bf, z);
            acc[1][ct] = MFMA16(cA1, bf, z);
        }
        __syncthreads();
#pragma unroll
        for (int mt = 0; mt < 2; ++mt)
#pragma unroll
            for (int ct = 0; ct < 4; ++ct)
#pragma unroll
                for (int i = 0; i < 4; ++i)
                    Ha[(mt * 16 + q * 4 + i) * 72 + ct * 16 + r] =
                        (_Float16)acc[mt][ct][i];
    }
    __syncthreads();

    // ---- MLP1a: relu(Ha @ w1a + b1a) -> Ha (in-place) ----
    mlp_core<2>(Ha, wf, 12, b1a, q, r, l, acc);
    __syncthreads();
#pragma unroll
    for (int mt = 0; mt < 2; ++mt)
#pragma unroll
        for (int ct = 0; ct < 4; ++ct)
#pragma unroll
            for (int i = 0; i < 4; ++i)
                Ha[(mt * 16 + q * 4 + i) * 72 + ct * 16 + r] =
                    (_Float16)fmaxf(acc[mt][ct][i], 0.f);
    __syncthreads();

    // ---- MLP1b + relu + mean pool ----
    mlp_core<2>(Ha, wf, 20, b1b, q, r, l, acc);
    float ps[4];
#pragma unroll
    for (int ct = 0; ct < 4; ++ct) {
        ps[ct] = 0.f;
#pragma unroll
        for (int mt = 0; mt < 2; ++mt)
#pragma unroll
            for (int i = 0; i < 4; ++i) ps[ct] += fmaxf(acc[mt][ct][i], 0.f);
        ps[ct] += __shfl_xor(ps[ct], 16, 64);
        ps[ct] += __shfl_xor(ps[ct], 32, 64);
    }
    __syncthreads();
    float* hg = (float*)Ha;
    if (l < 16) {
#pragma unroll
        for (int ct = 0; ct < 4; ++ct) hg[ct * 16 + l] = ps[ct] * (1.f / 32.f);
    }
    __syncthreads();

    // ---- scorer: relu(hg @ ws1 + bs1) @ ws2 + bs2 ----
    float acc0 = bs1[l];
#pragma unroll
    for (int kq = 0; kq < 16; ++kq) {
        const float4 h4 = *reinterpret_cast<const float4*>(&hg[kq * 4]);
        acc0 = fmaf(h4.x, ws1[(kq * 4 + 0) * 64 + l], acc0);
        acc0 = fmaf(h4.y, ws1[(kq * 4 + 1) * 64 + l], acc0);
        acc0 = fmaf(h4.z, ws1[(kq * 4 + 2) * 64 + l], acc0);
        acc0 = fmaf(h4.w, ws1[(kq * 4 + 3) * 64 + l], acc0);
    }
    float p = fmaxf(acc0, 0.f) * ws2[l];
#pragma unroll
    for (int off = 32; off > 0; off >>= 1) p += __shfl_xor(p, off, 64);
    if (l == 0) out[g] = p + bs2[0];
}

// ---------------------------------------------------------------------------
extern "C" void kernel_launch(void* const* d_in, const int* in_sizes, int n_in,
                              void* d_out, int out_size, void* d_ws,
                              size_t ws_size, hipStream_t stream) {
    const int* labels = (const int*)d_in[0];
    const int* src = (const int*)d_in[1];
    const int* dst = (const int*)d_in[2];
    const float* emb = (const float*)d_in[4];
    const float* w0a = (const float*)d_in[5];
    const float* b0a = (const float*)d_in[6];
    const float* w0b = (const float*)d_in[7];
    const float* b0b = (const float*)d_in[8];
    const float* w1a = (const float*)d_in[9];
    const float* b1a = (const float*)d_in[10];
    const float* w1b = (const float*)d_in[11];
    const float* b1b = (const float*)d_in[12];
    const float* ws1 = (const float*)d_in[13];
    const float* bs1 = (const float*)d_in[14];
    const float* ws2 = (const float*)d_in[15];
    const float* bs2 = (const float*)d_in[16];
    float* out = (float*)d_out;

    const int N = in_sizes[0];  // 262144 nodes
    const int E = in_sizes[1];  // 2097152 edges
    const int Gn = out_size;    // 8192 subgraphs

    // ws layout: cnt (N*16 B) | wf (57344 B) | gFill (1 KB) | packed (10 MB)
    unsigned* cnt = (unsigned*)d_ws;
    _Float16* wf = (_Float16*)((char*)d_ws + (size_t)N * 16);
    unsigned* gFill = (unsigned*)((char*)d_ws + (size_t)N * 16 + 57344);
    unsigned* packed = (unsigned*)((char*)d_ws + (size_t)N * 16 + 57344 + 1024);

    hipMemsetAsync(gFill, 0, BUCKETS * sizeof(unsigned), stream);
    const int E4 = E / 4;
    part_edges<<<(E4 + 2047) / 2048, 256, 0, stream>>>(
        (const int4*)src, (const int4*)dst, E4, gFill, packed);
    count_edges<<<Gn / 32, 256, 0, stream>>>(gFill, packed, cnt);
    prep_w<<<28, 64, 0, stream>>>(w0a, w0b, w1a, w1b, wf);
    seal_fused<<<Gn, 64, 0, stream>>>(labels, emb, b0a, b0b, b1a, b1b, ws1,
                                      bs1, ws2, bs2, cnt, wf, out);
}

// Round 6
// 70.702 us; speedup vs baseline: 2.0754x; 1.1015x over previous
//
#include <hip/hip_runtime.h>

#define NPG 32
#define BUCKETS 256
#define BCAP 10240  // per-bucket capacity: mean 8192, sigma ~88

typedef _Float16 half8 __attribute__((ext_vector_type(8)));
typedef _Float16 half4v __attribute__((ext_vector_type(4)));
typedef float f32x4 __attribute__((ext_vector_type(4)));

#define MFMA16(a, b, c) __builtin_amdgcn_mfma_f32_16x16x32_f16(a, b, c, 0, 0, 0)

// ---------------------------------------------------------------------------
// K0: weight prep (also zeroes gFill so no hipMemsetAsync is needed).
// Per 16x16x32 B-tile (kt,ct): lane l holds W[kt*32+(l>>4)*8+j][ct*16+(l&15)]
// as f16 hi plane + f16 lo plane. [w0a:0..3][w0b:4..11][w1a:12..19][w1b:20..27]
// ---------------------------------------------------------------------------
__global__ __launch_bounds__(64) void prep_w(const float* __restrict__ w0a,
                                             const float* __restrict__ w0b,
                                             const float* __restrict__ w1a,
                                             const float* __restrict__ w1b,
                                             _Float16* __restrict__ wf,
                                             unsigned* __restrict__ gFill) {
    int b = blockIdx.x;  // 0..27
    int l = threadIdx.x;
    if (b == 0) {
#pragma unroll
        for (int i = 0; i < 4; ++i) gFill[i * 64 + l] = 0u;
    }
    const float* W;
    int fi;
    if (b < 4) {
        W = w0a; fi = b;
    } else if (b < 12) {
        W = w0b; fi = b - 4;
    } else if (b < 20) {
        W = w1a; fi = b - 12;
    } else {
        W = w1b; fi = b - 20;
    }
    int kt = fi >> 2, ct = fi & 3;
    int q = l >> 4, r = l & 15;
    half8 hi, lo;
#pragma unroll
    for (int j = 0; j < 8; ++j) {
        float w = W[(kt * 32 + q * 8 + j) * 64 + ct * 16 + r];
        _Float16 h = (_Float16)w;
        hi[j] = h;
        lo[j] = (_Float16)(w - (float)h);
    }
    *(half8*)(wf + b * 1024 + l * 8) = hi;
    *(half8*)(wf + b * 1024 + 512 + l * 8) = lo;
}

// ---------------------------------------------------------------------------
// K1: partition edges into 256 buckets (32 graphs each). LDS histogram,
// one global atomic per (block,bucket), LDS-cursor scatter of (d<<5)|s.
// ---------------------------------------------------------------------------
__global__ __launch_bounds__(256) void part_edges(
    const int4* __restrict__ src4, const int4* __restrict__ dst4, int E4,
    unsigned* __restrict__ gFill, unsigned* __restrict__ packed) {
    __shared__ unsigned hist[BUCKETS];
    __shared__ unsigned cursor[BUCKETS];
    const int t = threadIdx.x;
    const int b4 = blockIdx.x * 2048;
    unsigned pk[32];
#pragma unroll
    for (int k = 0; k < 8; ++k) {
        int i4 = b4 + k * 256 + t;
        if (i4 < E4) {
            int4 s4 = src4[i4];
            int4 d4 = dst4[i4];
#pragma unroll
            for (int j = 0; j < 4; ++j) {
                unsigned d = (unsigned)((const int*)&d4)[j];
                unsigned s = (unsigned)((const int*)&s4)[j] & 31u;
                pk[k * 4 + j] = (d << 5) | s;  // bucket=pk>>15
            }
        } else {
#pragma unroll
            for (int j = 0; j < 4; ++j) pk[k * 4 + j] = 0xFFFFFFFFu;
        }
    }
    hist[t] = 0;
    __syncthreads();
#pragma unroll
    for (int k = 0; k < 32; ++k)
        if (pk[k] != 0xFFFFFFFFu) atomicAdd(&hist[pk[k] >> 15], 1u);
    __syncthreads();
    cursor[t] = atomicAdd(&gFill[t], hist[t]);
    __syncthreads();
#pragma unroll
    for (int k = 0; k < 32; ++k) {
        if (pk[k] == 0xFFFFFFFFu) continue;
        unsigned b = pk[k] >> 15;
        unsigned slot = atomicAdd(&cursor[b], 1u);
        if (slot < BCAP) packed[b * BCAP + slot] = pk[k];
    }
}

// ---------------------------------------------------------------------------
// K2: per bucket, nibble-packed counts for its 32 graphs in LDS, linear write.
// cnt[node*4+w] == b*4096 + gl*128 + d*4 + w.
// ---------------------------------------------------------------------------
__global__ __launch_bounds__(256) void count_edges(
    const unsigned* __restrict__ gFill, const unsigned* __restrict__ packed,
    unsigned* __restrict__ cnt) {
    __shared__ unsigned C[32 * 128];
    const int b = blockIdx.x, t = threadIdx.x;
#pragma unroll
    for (int i = 0; i < 16; ++i) C[i * 256 + t] = 0;
    __syncthreads();
    unsigned n = gFill[b];
    if (n > BCAP) n = BCAP;
    const unsigned* pb = packed + (size_t)b * BCAP;
    for (unsigned i = t; i < n; i += 256) {
        unsigned pk = pb[i];
        unsigned gl = (pk >> 10) & 31u, d = (pk >> 5) & 31u, s = pk & 31u;
        atomicAdd(&C[gl * 128 + d * 4 + (s >> 3)], 1u << (4 * (s & 7)));
    }
    __syncthreads();
    unsigned* cg = cnt + (size_t)b * 4096;
#pragma unroll
    for (int i = 0; i < 16; ++i) cg[i * 256 + t] = C[i * 256 + t];
}

// ---------------------------------------------------------------------------
// K3: fused model. ONE wave per TWO subgraphs (M=64 = 2 x 32 nodes, mt=0..3).
// Weight frags feed both graphs -> weight traffic/graph halved. Single 9.2KB
// activation buffer reused row-major/feat-major (full reg-staging before each
// overwrite; single-wave in-order LDS => no barriers). LDS 14.3KB -> 11 wg/CU.
// ---------------------------------------------------------------------------
__global__ __launch_bounds__(64, 3) void seal_fused(
    const int* __restrict__ labels, const float* __restrict__ emb,
    const float* __restrict__ b0a, const float* __restrict__ b0b,
    const float* __restrict__ b1a, const float* __restrict__ b1b,
    const float* __restrict__ ws1, const float* __restrict__ bs1,
    const float* __restrict__ ws2, const float* __restrict__ bs2,
    const uint4* __restrict__ cnt4, const _Float16* __restrict__ wf,
    float* __restrict__ out) {
    const int wg = blockIdx.x;  // graphs 2wg, 2wg+1
    const int l = threadIdx.x;
    const int q = l >> 4, r = l & 15;

    __shared__ __align__(16) _Float16 Act[64 * 72];
    __shared__ __align__(16) _Float16 Cn[2][32 * 40];

    // ---- counts: lane -> (graph l>>5, dest d=l&31); unpack 16 nibbles ----
    {
        int gsel = l >> 5, d = l & 31;
        uint4 cw = cnt4[((size_t)wg * 2 + gsel) * 32 + d];
        unsigned w[4] = {cw.x, cw.y, cw.z, cw.w};
#pragma unroll
        for (int wi = 0; wi < 4; ++wi)
#pragma unroll
            for (int i = 0; i < 8; ++i) {
                int s = wi * 8 + i;
                float v = (float)((w[wi] >> (4 * i)) & 15u) +
                          (s == d ? 1.f : 0.f);
                Cn[gsel][d * 40 + s] = (_Float16)v;
            }
    }

    // ---- embedding -> feat-major Act[f][node l] (node slots 0..63) ----
    {
        int g = wg * 2 + (l >> 5), nl = l & 31;
        int lab = labels[g * NPG + nl];
        lab = min(max(lab, 0), 50);
        float m = (lab != 0) ? 1.f : 0.f;
        const f32x4* er = (const f32x4*)(emb + lab * 32);
#pragma unroll
        for (int c4 = 0; c4 < 8; ++c4) {
            f32x4 v = er[c4];
#pragma unroll
            for (int k = 0; k < 4; ++k)
                Act[(c4 * 4 + k) * 72 + l] = (_Float16)(v[k] * m);
        }
    }

    // ---- Cn A-frags, persistent for both aggs ----
    half8 cA[4];
#pragma unroll
    for (int mt = 0; mt < 4; ++mt)
        cA[mt] = *(const half8*)&Cn[mt >> 1][((mt & 1) * 16 + r) * 40 + q * 8];

    f32x4 acc[4][4];
    const f32x4 z4 = {0.f, 0.f, 0.f, 0.f};

    // ---- agg0: D[64n][32f] = blockdiag(C0,C1) @ H0 ; B from feat-major ----
    {
        half8 bf[2][2];
#pragma unroll
        for (int gi = 0; gi < 2; ++gi)
#pragma unroll
            for (int ct = 0; ct < 2; ++ct)
                bf[gi][ct] =
                    *(const half8*)&Act[(ct * 16 + r) * 72 + gi * 32 + q * 8];
#pragma unroll
        for (int mt = 0; mt < 4; ++mt)
#pragma unroll
            for (int ct = 0; ct < 2; ++ct)
                acc[mt][ct] = MFMA16(cA[mt], bf[mt >> 1][ct], z4);
#pragma unroll
        for (int mt = 0; mt < 4; ++mt)
#pragma unroll
            for (int ct = 0; ct < 2; ++ct)
#pragma unroll
                for (int i = 0; i < 4; ++i)
                    Act[(mt * 16 + q * 4 + i) * 72 + ct * 16 + r] =
                        (_Float16)acc[mt][ct][i];
    }

    // ---- MLP0a: relu(Act[64x32] @ w0a + b0a) -> row-major in-place ----
    {
        half8 A[4];
#pragma unroll
        for (int mt = 0; mt < 4; ++mt)
            A[mt] = *(const half8*)&Act[(mt * 16 + r) * 72 + q * 8];
#pragma unroll
        for (int ct = 0; ct < 4; ++ct) {
            float b = b0a[ct * 16 + r];
            const _Float16* base = wf + (0 + ct) * 1024;
            half8 whi = *(const half8*)(base + l * 8);
            half8 wlo = *(const half8*)(base + 512 + l * 8);
#pragma unroll
            for (int mt = 0; mt < 4; ++mt) {
                f32x4 a = {b, b, b, b};
                a = MFMA16(A[mt], whi, a);
                a = MFMA16(A[mt], wlo, a);
                acc[mt][ct] = a;
            }
        }
#pragma unroll
        for (int mt = 0; mt < 4; ++mt)
#pragma unroll
            for (int ct = 0; ct < 4; ++ct)
#pragma unroll
                for (int i = 0; i < 4; ++i)
                    Act[(mt * 16 + q * 4 + i) * 72 + ct * 16 + r] =
                        (_Float16)fmaxf(acc[mt][ct][i], 0.f);
    }

    // ---- MLP0b: relu(Act[64x64] @ w0b + b0b) -> feat-major ----
    {
        half8 A[4][2];
#pragma unroll
        for (int mt = 0; mt < 4; ++mt)
#pragma unroll
            for (int kt = 0; kt < 2; ++kt)
                A[mt][kt] =
                    *(const half8*)&Act[(mt * 16 + r) * 72 + kt * 32 + q * 8];
#pragma unroll
        for (int ct = 0; ct < 4; ++ct) {
            float b = b0b[ct * 16 + r];
            f32x4 a[4] = {{b, b, b, b}, {b, b, b, b}, {b, b, b, b}, {b, b, b, b}};
#pragma unroll
            for (int kt = 0; kt < 2; ++kt) {
                const _Float16* base = wf + (4 + kt * 4 + ct) * 1024;
                half8 whi = *(const half8*)(base + l * 8);
                half8 wlo = *(const half8*)(base + 512 + l * 8);
#pragma unroll
                for (int mt = 0; mt < 4; ++mt) {
                    a[mt] = MFMA16(A[mt][kt], whi, a[mt]);
                    a[mt] = MFMA16(A[mt][kt], wlo, a[mt]);
                }
            }
#pragma unroll
            for (int mt = 0; mt < 4; ++mt) acc[mt][ct] = a[mt];
        }
#pragma unroll
        for (int mt = 0; mt < 4; ++mt)
#pragma unroll
            for (int ct = 0; ct < 4; ++ct) {
                half4v p;
#pragma unroll
                for (int i = 0; i < 4; ++i)
                    p[i] = (_Float16)fmaxf(acc[mt][ct][i], 0.f);
                *(half4v*)&Act[(ct * 16 + r) * 72 + mt * 16 + q * 4] = p;
            }
    }

    // ---- agg1: D[64n][64f] = blockdiag(C0,C1) @ H1 -> row-major ----
    {
        half8 bf[2][4];
#pragma unroll
        for (int gi = 0; gi < 2; ++gi)
#pragma unroll
            for (int ct = 0; ct < 4; ++ct)
                bf[gi][ct] =
                    *(const half8*)&Act[(ct * 16 + r) * 72 + gi * 32 + q * 8];
#pragma unroll
        for (int mt = 0; mt < 4; ++mt)
#pragma unroll
            for (int ct = 0; ct < 4; ++ct)
                acc[mt][ct] = MFMA16(cA[mt], bf[mt >> 1][ct], z4);
#pragma unroll
        for (int mt = 0; mt < 4; ++mt)
#pragma unroll
            for (int ct = 0; ct < 4; ++ct)
#pragma unroll
                for (int i = 0; i < 4; ++i)
                    Act[(mt * 16 + q * 4 + i) * 72 + ct * 16 + r] =
                        (_Float16)acc[mt][ct][i];
    }

    // ---- MLP1a: relu(Act @ w1a + b1a) -> row-major in-place ----
    {
        half8 A[4][2];
#pragma unroll
        for (int mt = 0; mt < 4; ++mt)
#pragma unroll
            for (int kt = 0; kt < 2; ++kt)
                A[mt][kt] =
                    *(const half8*)&Act[(mt * 16 + r) * 72 + kt * 32 + q * 8];
#pragma unroll
        for (int ct = 0; ct < 4; ++ct) {
            float b = b1a[ct * 16 + r];
            f32x4 a[4] = {{b, b, b, b}, {b, b, b, b}, {b, b, b, b}, {b, b, b, b}};
#pragma unroll
            for (int kt = 0; kt < 2; ++kt) {
                const _Float16* base = wf + (12 + kt * 4 + ct) * 1024;
                half8 whi = *(const half8*)(base + l * 8);
                half8 wlo = *(const half8*)(base + 512 + l * 8);
#pragma unroll
                for (int mt = 0; mt < 4; ++mt) {
                    a[mt] = MFMA16(A[mt][kt], whi, a[mt]);
                    a[mt] = MFMA16(A[mt][kt], wlo, a[mt]);
                }
            }
#pragma unroll
            for (int mt = 0; mt < 4; ++mt) acc[mt][ct] = a[mt];
        }
#pragma unroll
        for (int mt = 0; mt < 4; ++mt)
#pragma unroll
            for (int ct = 0; ct < 4; ++ct)
#pragma unroll
                for (int i = 0; i < 4; ++i)
                    Act[(mt * 16 + q * 4 + i) * 72 + ct * 16 + r] =
                        (_Float16)fmaxf(acc[mt][ct][i], 0.f);
    }

    // ---- MLP1b + relu + per-graph mean pool ----
    float ps[2][4];
    {
        half8 A[4][2];
#pragma unroll
        for (int mt = 0; mt < 4; ++mt)
#pragma unroll
            for (int kt = 0; kt < 2; ++kt)
                A[mt][kt] =
                    *(const half8*)&Act[(mt * 16 + r) * 72 + kt * 32 + q * 8];
#pragma unroll
        for (int ct = 0; ct < 4; ++ct) {
            float b = b1b[ct * 16 + r];
            f32x4 a[4] = {{b, b, b, b}, {b, b, b, b}, {b, b, b, b}, {b, b, b, b}};
#pragma unroll
            for (int kt = 0; kt < 2; ++kt) {
                const _Float16* base = wf + (20 + kt * 4 + ct) * 1024;
                half8 whi = *(const half8*)(base + l * 8);
                half8 wlo = *(const half8*)(base + 512 + l * 8);
#pragma unroll
                for (int mt = 0; mt < 4; ++mt) {
                    a[mt] = MFMA16(A[mt][kt], whi, a[mt]);
                    a[mt] = MFMA16(A[mt][kt], wlo, a[mt]);
                }
            }
#pragma unroll
            for (int gi = 0; gi < 2; ++gi) {
                float s = 0.f;
#pragma unroll
                for (int m2 = 0; m2 < 2; ++m2)
#pragma unroll
                    for (int i = 0; i < 4; ++i)
                        s += fmaxf(a[gi * 2 + m2][i], 0.f);
                ps[gi][ct] = s;
            }
        }
    }
#pragma unroll
    for (int gi = 0; gi < 2; ++gi)
#pragma unroll
        for (int ct = 0; ct < 4; ++ct) {
            ps[gi][ct] += __shfl_xor(ps[gi][ct], 16, 64);
            ps[gi][ct] += __shfl_xor(ps[gi][ct], 32, 64);
        }
    float* F = (float*)Act;
    if (l < 16) {
#pragma unroll
        for (int gi = 0; gi < 2; ++gi)
#pragma unroll
            for (int ct = 0; ct < 4; ++ct)
                F[gi * 64 + ct * 16 + l] = ps[gi][ct] * (1.f / 32.f);
    }

    // ---- scorer: relu(hg @ ws1 + bs1) @ ws2 + bs2 (fp32, both graphs) ----
    float a0 = bs1[l], a1 = a0;
#pragma unroll
    for (int kq = 0; kq < 16; ++kq) {
        f32x4 f0 = *(const f32x4*)&F[kq * 4];
        f32x4 f1 = *(const f32x4*)&F[64 + kq * 4];
#pragma unroll
        for (int j = 0; j < 4; ++j) {
            float wv = ws1[(kq * 4 + j) * 64 + l];
            a0 = fmaf(f0[j], wv, a0);
            a1 = fmaf(f1[j], wv, a1);
        }
    }
    float w2 = ws2[l];
    float p0 = fmaxf(a0, 0.f) * w2;
    float p1 = fmaxf(a1, 0.f) * w2;
#pragma unroll
    for (int off = 32; off > 0; off >>= 1) {
        p0 += __shfl_xor(p0, off, 64);
        p1 += __shfl_xor(p1, off, 64);
    }
    if (l == 0) {
        float b = bs2[0];
        out[wg * 2] = p0 + b;
        out[wg * 2 + 1] = p1 + b;
    }
}

// ---------------------------------------------------------------------------
extern "C" void kernel_launch(void* const* d_in, const int* in_sizes, int n_in,
                              void* d_out, int out_size, void* d_ws,
                              size_t ws_size, hipStream_t stream) {
    const int* labels = (const int*)d_in[0];
    const int* src = (const int*)d_in[1];
    const int* dst = (const int*)d_in[2];
    const float* emb = (const float*)d_in[4];
    const float* w0a = (const float*)d_in[5];
    const float* b0a = (const float*)d_in[6];
    const float* w0b = (const float*)d_in[7];
    const float* b0b = (const float*)d_in[8];
    const float* w1a = (const float*)d_in[9];
    const float* b1a = (const float*)d_in[10];
    const float* w1b = (const float*)d_in[11];
    const float* b1b = (const float*)d_in[12];
    const float* ws1 = (const float*)d_in[13];
    const float* bs1 = (const float*)d_in[14];
    const float* ws2 = (const float*)d_in[15];
    const float* bs2 = (const float*)d_in[16];
    float* out = (float*)d_out;

    const int N = in_sizes[0];  // 262144 nodes
    const int E = in_sizes[1];  // 2097152 edges
    const int Gn = out_size;    // 8192 subgraphs

    // ws layout: cnt (N*16 B) | wf (57344 B) | gFill (1 KB) | packed (10 MB)
    unsigned* cnt = (unsigned*)d_ws;
    _Float16* wf = (_Float16*)((char*)d_ws + (size_t)N * 16);
    unsigned* gFill = (unsigned*)((char*)d_ws + (size_t)N * 16 + 57344);
    unsigned* packed = (unsigned*)((char*)d_ws + (size_t)N * 16 + 57344 + 1024);

    const int E4 = E / 4;
    prep_w<<<28, 64, 0, stream>>>(w0a, w0b, w1a, w1b, wf, gFill);
    part_edges<<<(E4 + 2047) / 2048, 256, 0, stream>>>(
        (const int4*)src, (const int4*)dst, E4, gFill, packed);
    count_edges<<<Gn / 32, 256, 0, stream>>>(gFill, packed, cnt);
    seal_fused<<<Gn / 2, 64, 0, stream>>>(labels, emb, b0a, b0b, b1a, b1b, ws1,
                                          bs1, ws2, bs2, (const uint4*)cnt, wf,
                                          out);
}

// Round 7
// 64.803 us; speedup vs baseline: 2.2644x; 1.0910x over previous
//
#include <hip/hip_runtime.h>

#define NPG 32
#define BUCKETS 1024       // 8 graphs per bucket
#define BCAP 2560          // mean 2048, sigma ~45 -> +11 sigma

typedef _Float16 half8 __attribute__((ext_vector_type(8)));
typedef _Float16 half4v __attribute__((ext_vector_type(4)));
typedef float f32x4 __attribute__((ext_vector_type(4)));

#define MFMA16(a, b, c) __builtin_amdgcn_mfma_f32_16x16x32_f16(a, b, c, 0, 0, 0)

// ---------------------------------------------------------------------------
// K0: weight prep (also zeroes gFill). Per 16x16x32 B-tile (kt,ct): lane l
// holds W[kt*32+(l>>4)*8+j][ct*16+(l&15)] as f16 hi + f16 lo (residual).
// [w0a:0..3][w0b:4..11][w1a:12..19][w1b:20..27]
// ---------------------------------------------------------------------------
__global__ __launch_bounds__(64) void prep_w(const float* __restrict__ w0a,
                                             const float* __restrict__ w0b,
                                             const float* __restrict__ w1a,
                                             const float* __restrict__ w1b,
                                             _Float16* __restrict__ wf,
                                             unsigned* __restrict__ gFill) {
    int b = blockIdx.x;  // 0..27
    int l = threadIdx.x;
    if (b == 0) {
#pragma unroll
        for (int i = 0; i < 16; ++i) gFill[i * 64 + l] = 0u;
    }
    const float* W;
    int fi;
    if (b < 4) {
        W = w0a; fi = b;
    } else if (b < 12) {
        W = w0b; fi = b - 4;
    } else if (b < 20) {
        W = w1a; fi = b - 12;
    } else {
        W = w1b; fi = b - 20;
    }
    int kt = fi >> 2, ct = fi & 3;
    int q = l >> 4, r = l & 15;
    half8 hi, lo;
#pragma unroll
    for (int j = 0; j < 8; ++j) {
        float w = W[(kt * 32 + q * 8 + j) * 64 + ct * 16 + r];
        _Float16 h = (_Float16)w;
        hi[j] = h;
        lo[j] = (_Float16)(w - (float)h);
    }
    *(half8*)(wf + b * 1024 + l * 8) = hi;
    *(half8*)(wf + b * 1024 + 512 + l * 8) = lo;
}

// ---------------------------------------------------------------------------
// K1: partition edges into 1024 buckets (8 graphs each). LDS histogram, one
// global atomic per (block,bucket) to reserve, LDS-cursor scatter of u16
// payload (g&7)<<10 | d<<5 | s.
// ---------------------------------------------------------------------------
__global__ __launch_bounds__(256) void part_edges(
    const int4* __restrict__ src4, const int4* __restrict__ dst4, int E4,
    unsigned* __restrict__ gFill, unsigned short* __restrict__ packed) {
    __shared__ unsigned hist[BUCKETS];
    __shared__ unsigned cursor[BUCKETS];
    const int t = threadIdx.x;
    const int b4 = blockIdx.x * 2048;
    unsigned pk[32];
#pragma unroll
    for (int k = 0; k < 8; ++k) {
        int i4 = b4 + k * 256 + t;
        if (i4 < E4) {
            int4 s4 = src4[i4];
            int4 d4 = dst4[i4];
#pragma unroll
            for (int j = 0; j < 4; ++j) {
                unsigned d = (unsigned)((const int*)&d4)[j];
                unsigned s = (unsigned)((const int*)&s4)[j] & 31u;
                pk[k * 4 + j] = (d << 5) | s;  // bucket = pk>>13
            }
        } else {
#pragma unroll
            for (int j = 0; j < 4; ++j) pk[k * 4 + j] = 0xFFFFFFFFu;
        }
    }
#pragma unroll
    for (int i = 0; i < 4; ++i) hist[i * 256 + t] = 0;
    __syncthreads();
#pragma unroll
    for (int k = 0; k < 32; ++k)
        if (pk[k] != 0xFFFFFFFFu) atomicAdd(&hist[pk[k] >> 13], 1u);
    __syncthreads();
#pragma unroll
    for (int i = 0; i < 4; ++i) {
        int b = i * 256 + t;
        cursor[b] = atomicAdd(&gFill[b], hist[b]);
    }
    __syncthreads();
#pragma unroll
    for (int k = 0; k < 32; ++k) {
        if (pk[k] == 0xFFFFFFFFu) continue;
        unsigned b = pk[k] >> 13;
        unsigned slot = atomicAdd(&cursor[b], 1u);
        if (slot < BCAP)
            packed[(size_t)b * BCAP + slot] = (unsigned short)(pk[k] & 0x1FFFu);
    }
}

// ---------------------------------------------------------------------------
// K2: fused model. One block (4 waves) per 8-graph bucket: stream bucket
// edges -> nibble counts for 8 graphs in LDS (4KB); then each wave runs the
// 2-graph MFMA pipeline in its private 9.2KB Act buffer (no barriers inside).
// LDS = 4KB cnt + 4x9216 Act = 40KB -> 3-4 blocks/CU.
// ---------------------------------------------------------------------------
__global__ __launch_bounds__(256, 3) void seal_fused(
    const int* __restrict__ labels, const float* __restrict__ emb,
    const float* __restrict__ b0a, const float* __restrict__ b0b,
    const float* __restrict__ b1a, const float* __restrict__ b1b,
    const float* __restrict__ ws1, const float* __restrict__ bs1,
    const float* __restrict__ ws2, const float* __restrict__ bs2,
    const unsigned* __restrict__ gFill, const unsigned short* __restrict__ pkd,
    const _Float16* __restrict__ wf, float* __restrict__ out) {
    const int b = blockIdx.x;  // bucket: graphs b*8 .. b*8+7
    const int tid = threadIdx.x;
    const int wid = tid >> 6, l = tid & 63;
    const int q = l >> 4, r = l & 15;

    __shared__ unsigned cntL[8 * 128];  // [graph][d][word] nibble-packed, 4KB
    __shared__ __align__(16) _Float16 ActAll[4][64 * 72];

    // ---- build counts for the 8 graphs from bucket edges ----
#pragma unroll
    for (int i = 0; i < 4; ++i) cntL[i * 256 + tid] = 0;
    __syncthreads();
    {
        unsigned n = gFill[b];
        if (n > BCAP) n = BCAP;
        const unsigned short* pb = pkd + (size_t)b * BCAP;
        for (unsigned i = tid; i < n; i += 256) {
            unsigned pk = pb[i];
            atomicAdd(&cntL[((pk >> 10) & 7u) * 128 + ((pk >> 5) & 31u) * 4 +
                            ((pk & 31u) >> 3)],
                      1u << (4 * (pk & 7u)));
        }
    }

    _Float16* Act = ActAll[wid];
    const int g0 = b * 8 + wid * 2;  // this wave's graph pair

    // ---- embedding -> feat-major Act[f][node l] (overlaps count phase) ----
    {
        int gsel = l >> 5, nl = l & 31;
        int lab = labels[(g0 + gsel) * NPG + nl];
        lab = min(max(lab, 0), 50);
        float m = (lab != 0) ? 1.f : 0.f;
        const f32x4* er = (const f32x4*)(emb + lab * 32);
#pragma unroll
        for (int c4 = 0; c4 < 8; ++c4) {
            f32x4 v = er[c4];
#pragma unroll
            for (int k = 0; k < 4; ++k)
                Act[(c4 * 4 + k) * 72 + l] = (_Float16)(v[k] * m);
        }
    }
    __syncthreads();  // counts ready

    // ---- cA frags: unpack nibbles from cntL, add I ----
    half8 cA[4];
#pragma unroll
    for (int mt = 0; mt < 4; ++mt) {
        int gg = wid * 2 + (mt >> 1);
        int d = (mt & 1) * 16 + r;
        unsigned c = cntL[gg * 128 + d * 4 + q];
        half8 f;
#pragma unroll
        for (int j = 0; j < 8; ++j) {
            int s = q * 8 + j;
            float v = (float)((c >> (4 * j)) & 15u) + (s == d ? 1.f : 0.f);
            f[j] = (_Float16)v;
        }
        cA[mt] = f;
    }

    f32x4 acc[4][4];
    const f32x4 z4 = {0.f, 0.f, 0.f, 0.f};

    // ---- agg0: D[64n][32f] = blockdiag(C0,C1) @ H0 ; B from feat-major ----
    {
        half8 bf[2][2];
#pragma unroll
        for (int gi = 0; gi < 2; ++gi)
#pragma unroll
            for (int ct = 0; ct < 2; ++ct)
                bf[gi][ct] =
                    *(const half8*)&Act[(ct * 16 + r) * 72 + gi * 32 + q * 8];
#pragma unroll
        for (int mt = 0; mt < 4; ++mt)
#pragma unroll
            for (int ct = 0; ct < 2; ++ct)
                acc[mt][ct] = MFMA16(cA[mt], bf[mt >> 1][ct], z4);
#pragma unroll
        for (int mt = 0; mt < 4; ++mt)
#pragma unroll
            for (int ct = 0; ct < 2; ++ct)
#pragma unroll
                for (int i = 0; i < 4; ++i)
                    Act[(mt * 16 + q * 4 + i) * 72 + ct * 16 + r] =
                        (_Float16)acc[mt][ct][i];
    }

    // ---- MLP0a: relu(Act[64x32] @ w0a + b0a) -> row-major in-place ----
    {
        half8 A[4];
#pragma unroll
        for (int mt = 0; mt < 4; ++mt)
            A[mt] = *(const half8*)&Act[(mt * 16 + r) * 72 + q * 8];
#pragma unroll
        for (int ct = 0; ct < 4; ++ct) {
            float b_ = b0a[ct * 16 + r];
            const _Float16* base = wf + (0 + ct) * 1024;
            half8 whi = *(const half8*)(base + l * 8);
            half8 wlo = *(const half8*)(base + 512 + l * 8);
#pragma unroll
            for (int mt = 0; mt < 4; ++mt) {
                f32x4 a = {b_, b_, b_, b_};
                a = MFMA16(A[mt], whi, a);
                a = MFMA16(A[mt], wlo, a);
                acc[mt][ct] = a;
            }
        }
#pragma unroll
        for (int mt = 0; mt < 4; ++mt)
#pragma unroll
            for (int ct = 0; ct < 4; ++ct)
#pragma unroll
                for (int i = 0; i < 4; ++i)
                    Act[(mt * 16 + q * 4 + i) * 72 + ct * 16 + r] =
                        (_Float16)fmaxf(acc[mt][ct][i], 0.f);
    }

    // ---- MLP0b: relu(Act[64x64] @ w0b + b0b) -> feat-major ----
    {
        half8 A[4][2];
#pragma unroll
        for (int mt = 0; mt < 4; ++mt)
#pragma unroll
            for (int kt = 0; kt < 2; ++kt)
                A[mt][kt] =
                    *(const half8*)&Act[(mt * 16 + r) * 72 + kt * 32 + q * 8];
#pragma unroll
        for (int ct = 0; ct < 4; ++ct) {
            float b_ = b0b[ct * 16 + r];
            f32x4 a[4] = {{b_, b_, b_, b_}, {b_, b_, b_, b_},
                          {b_, b_, b_, b_}, {b_, b_, b_, b_}};
#pragma unroll
            for (int kt = 0; kt < 2; ++kt) {
                const _Float16* base = wf + (4 + kt * 4 + ct) * 1024;
                half8 whi = *(const half8*)(base + l * 8);
                half8 wlo = *(const half8*)(base + 512 + l * 8);
#pragma unroll
                for (int mt = 0; mt < 4; ++mt) {
                    a[mt] = MFMA16(A[mt][kt], whi, a[mt]);
                    a[mt] = MFMA16(A[mt][kt], wlo, a[mt]);
                }
            }
#pragma unroll
            for (int mt = 0; mt < 4; ++mt) acc[mt][ct] = a[mt];
        }
#pragma unroll
        for (int mt = 0; mt < 4; ++mt)
#pragma unroll
            for (int ct = 0; ct < 4; ++ct) {
                half4v p;
#pragma unroll
                for (int i = 0; i < 4; ++i)
                    p[i] = (_Float16)fmaxf(acc[mt][ct][i], 0.f);
                *(half4v*)&Act[(ct * 16 + r) * 72 + mt * 16 + q * 4] = p;
            }
    }

    // ---- agg1: D[64n][64f] = blockdiag(C0,C1) @ H1 -> row-major ----
    {
        half8 bf[2][4];
#pragma unroll
        for (int gi = 0; gi < 2; ++gi)
#pragma unroll
            for (int ct = 0; ct < 4; ++ct)
                bf[gi][ct] =
                    *(const half8*)&Act[(ct * 16 + r) * 72 + gi * 32 + q * 8];
#pragma unroll
        for (int mt = 0; mt < 4; ++mt)
#pragma unroll
            for (int ct = 0; ct < 4; ++ct)
                acc[mt][ct] = MFMA16(cA[mt], bf[mt >> 1][ct], z4);
#pragma unroll
        for (int mt = 0; mt < 4; ++mt)
#pragma unroll
            for (int ct = 0; ct < 4; ++ct)
#pragma unroll
                for (int i = 0; i < 4; ++i)
                    Act[(mt * 16 + q * 4 + i) * 72 + ct * 16 + r] =
                        (_Float16)acc[mt][ct][i];
    }

    // ---- MLP1a: relu(Act @ w1a + b1a) -> row-major in-place ----
    {
        half8 A[4][2];
#pragma unroll
        for (int mt = 0; mt < 4; ++mt)
#pragma unroll
            for (int kt = 0; kt < 2; ++kt)
                A[mt][kt] =
                    *(const half8*)&Act[(mt * 16 + r) * 72 + kt * 32 + q * 8];
#pragma unroll
        for (int ct = 0; ct < 4; ++ct) {
            float b_ = b1a[ct * 16 + r];
            f32x4 a[4] = {{b_, b_, b_, b_}, {b_, b_, b_, b_},
                          {b_, b_, b_, b_}, {b_, b_, b_, b_}};
#pragma unroll
            for (int kt = 0; kt < 2; ++kt) {
                const _Float16* base = wf + (12 + kt * 4 + ct) * 1024;
                half8 whi = *(const half8*)(base + l * 8);
                half8 wlo = *(const half8*)(base + 512 + l * 8);
#pragma unroll
                for (int mt = 0; mt < 4; ++mt) {
                    a[mt] = MFMA16(A[mt][kt], whi, a[mt]);
                    a[mt] = MFMA16(A[mt][kt], wlo, a[mt]);
                }
            }
#pragma unroll
            for (int mt = 0; mt < 4; ++mt) acc[mt][ct] = a[mt];
        }
#pragma unroll
        for (int mt = 0; mt < 4; ++mt)
#pragma unroll
            for (int ct = 0; ct < 4; ++ct)
#pragma unroll
                for (int i = 0; i < 4; ++i)
                    Act[(mt * 16 + q * 4 + i) * 72 + ct * 16 + r] =
                        (_Float16)fmaxf(acc[mt][ct][i], 0.f);
    }

    // ---- MLP1b + relu + per-graph mean pool ----
    float ps[2][4];
    {
        half8 A[4][2];
#pragma unroll
        for (int mt = 0; mt < 4; ++mt)
#pragma unroll
            for (int kt = 0; kt < 2; ++kt)
                A[mt][kt] =
                    *(const half8*)&Act[(mt * 16 + r) * 72 + kt * 32 + q * 8];
#pragma unroll
        for (int ct = 0; ct < 4; ++ct) {
            float b_ = b1b[ct * 16 + r];
            f32x4 a[4] = {{b_, b_, b_, b_}, {b_, b_, b_, b_},
                          {b_, b_, b_, b_}, {b_, b_, b_, b_}};
#pragma unroll
            for (int kt = 0; kt < 2; ++kt) {
                const _Float16* base = wf + (20 + kt * 4 + ct) * 1024;
                half8 whi = *(const half8*)(base + l * 8);
                half8 wlo = *(const half8*)(base + 512 + l * 8);
#pragma unroll
                for (int mt = 0; mt < 4; ++mt) {
                    a[mt] = MFMA16(A[mt][kt], whi, a[mt]);
                    a[mt] = MFMA16(A[mt][kt], wlo, a[mt]);
                }
            }
#pragma unroll
            for (int gi = 0; gi < 2; ++gi) {
                float s = 0.f;
#pragma unroll
                for (int m2 = 0; m2 < 2; ++m2)
#pragma unroll
                    for (int i = 0; i < 4; ++i)
                        s += fmaxf(a[gi * 2 + m2][i], 0.f);
                ps[gi][ct] = s;
            }
        }
    }
#pragma unroll
    for (int gi = 0; gi < 2; ++gi)
#pragma unroll
        for (int ct = 0; ct < 4; ++ct) {
            ps[gi][ct] += __shfl_xor(ps[gi][ct], 16, 64);
            ps[gi][ct] += __shfl_xor(ps[gi][ct], 32, 64);
        }
    float* F = (float*)Act;
    if (l < 16) {
#pragma unroll
        for (int gi = 0; gi < 2; ++gi)
#pragma unroll
            for (int ct = 0; ct < 4; ++ct)
                F[gi * 64 + ct * 16 + l] = ps[gi][ct] * (1.f / 32.f);
    }

    // ---- scorer: relu(hg @ ws1 + bs1) @ ws2 + bs2 (fp32, both graphs) ----
    float a0 = bs1[l], a1 = a0;
#pragma unroll
    for (int kq = 0; kq < 16; ++kq) {
        f32x4 f0 = *(const f32x4*)&F[kq * 4];
        f32x4 f1 = *(const f32x4*)&F[64 + kq * 4];
#pragma unroll
        for (int j = 0; j < 4; ++j) {
            float wv = ws1[(kq * 4 + j) * 64 + l];
            a0 = fmaf(f0[j], wv, a0);
            a1 = fmaf(f1[j], wv, a1);
        }
    }
    float w2 = ws2[l];
    float p0 = fmaxf(a0, 0.f) * w2;
    float p1 = fmaxf(a1, 0.f) * w2;
#pragma unroll
    for (int off = 32; off > 0; off >>= 1) {
        p0 += __shfl_xor(p0, off, 64);
        p1 += __shfl_xor(p1, off, 64);
    }
    if (l == 0) {
        float bb = bs2[0];
        out[g0] = p0 + bb;
        out[g0 + 1] = p1 + bb;
    }
}

// ---------------------------------------------------------------------------
extern "C" void kernel_launch(void* const* d_in, const int* in_sizes, int n_in,
                              void* d_out, int out_size, void* d_ws,
                              size_t ws_size, hipStream_t stream) {
    const int* labels = (const int*)d_in[0];
    const int* src = (const int*)d_in[1];
    const int* dst = (const int*)d_in[2];
    const float* emb = (const float*)d_in[4];
    const float* w0a = (const float*)d_in[5];
    const float* b0a = (const float*)d_in[6];
    const float* w0b = (const float*)d_in[7];
    const float* b0b = (const float*)d_in[8];
    const float* w1a = (const float*)d_in[9];
    const float* b1a = (const float*)d_in[10];
    const float* w1b = (const float*)d_in[11];
    const float* b1b = (const float*)d_in[12];
    const float* ws1 = (const float*)d_in[13];
    const float* bs1 = (const float*)d_in[14];
    const float* ws2 = (const float*)d_in[15];
    const float* bs2 = (const float*)d_in[16];
    float* out = (float*)d_out;

    const int E = in_sizes[1];  // 2097152 edges
    const int Gn = out_size;    // 8192 subgraphs

    // ws layout: wf (57344 B) | gFill (4 KB) | packed16 (1024*2560*2 B)
    _Float16* wf = (_Float16*)d_ws;
    unsigned* gFill = (unsigned*)((char*)d_ws + 57344);
    unsigned short* packed =
        (unsigned short*)((char*)d_ws + 57344 + 4096);

    const int E4 = E / 4;
    prep_w<<<28, 64, 0, stream>>>(w0a, w0b, w1a, w1b, wf, gFill);
    part_edges<<<(E4 + 2047) / 2048, 256, 0, stream>>>(
        (const int4*)src, (const int4*)dst, E4, gFill, packed);
    seal_fused<<<Gn / 8, 256, 0, stream>>>(labels, emb, b0a, b0b, b1a, b1b,
                                           ws1, bs1, ws2, bs2, gFill, packed,
                                           wf, out);
}